// Round 7
// baseline (243.853 us; speedup 1.0000x reference)
//
#include <hip/hip_runtime.h>
#include <stdint.h>
#include <math.h>

typedef float  f32x4  __attribute__((ext_vector_type(4)));
typedef float  f32x16 __attribute__((ext_vector_type(16)));
typedef short  bf16x8 __attribute__((ext_vector_type(8)));
typedef unsigned int u32;
typedef unsigned int u32x4 __attribute__((ext_vector_type(4)));
typedef unsigned short ushort_t;

#define MFMA32(a, b, c) __builtin_amdgcn_mfma_f32_32x32x16_bf16((a), (b), (c), 0, 0, 0)

constexpr int B_ = 8, C_ = 128, N_ = 4096;
constexpr float LOG2E = 1.44269504088896340736f;

__device__ __forceinline__ u32 pack2bf(float a, float b) {  // RNE, a->lo16 b->hi16
  u32 ua = __builtin_bit_cast(u32, a);
  u32 ub = __builtin_bit_cast(u32, b);
  ua += 0x7fffu + ((ua >> 16) & 1u);
  ub += 0x7fffu + ((ub >> 16) & 1u);
  return (ua >> 16) | (ub & 0xffff0000u);
}
__device__ __forceinline__ u32 pkfast(float a, float b) {   // round-half-up, 3 ops
  u32 ua = __builtin_bit_cast(u32, a) + 0x8000u;
  u32 ub = __builtin_bit_cast(u32, b) + 0x8000u;
  return __builtin_amdgcn_perm(ub, ua, 0x07060302u);        // [b_hi16 : a_hi16]
}
__device__ __forceinline__ bf16x8 pack8(const float* v, float s) {
  u32x4 d = { pack2bf(v[0]*s, v[1]*s), pack2bf(v[2]*s, v[3]*s),
              pack2bf(v[4]*s, v[5]*s), pack2bf(v[6]*s, v[7]*s) };
  return __builtin_bit_cast(bf16x8, d);
}

// async global -> LDS, 16B per lane; lds dst is wave-uniform base (+lane*16 by HW)
__device__ __forceinline__ void gload_lds16(const ushort_t* g, ushort_t* l) {
  __builtin_amdgcn_global_load_lds(
      (const __attribute__((address_space(1))) void*)g,
      (__attribute__((address_space(3))) void*)l, 16, 0, 0);
}

// exp2 + bf16 pack + cross-half exchange -> one B-operand P fragment (16 j).
// Fully scalar (no vector ternary -> no scratch), native exp2, 2 bpermutes.
__device__ __forceinline__ bf16x8 mk_pa(const f32x16& sv, int rb, float& lacc,
                                        int lq1) {
  float e0 = __builtin_amdgcn_exp2f(sv[rb+0]);
  float e1 = __builtin_amdgcn_exp2f(sv[rb+1]);
  float e2 = __builtin_amdgcn_exp2f(sv[rb+2]);
  float e3 = __builtin_amdgcn_exp2f(sv[rb+3]);
  float e4 = __builtin_amdgcn_exp2f(sv[rb+4]);
  float e5 = __builtin_amdgcn_exp2f(sv[rb+5]);
  float e6 = __builtin_amdgcn_exp2f(sv[rb+6]);
  float e7 = __builtin_amdgcn_exp2f(sv[rb+7]);
  lacc += ((e0+e1)+(e2+e3)) + ((e4+e5)+(e6+e7));
  u32 a  = pkfast(e0, e1), b2 = pkfast(e2, e3);      // own j: 4lq1+{0..3}
  u32 c2 = pkfast(e4, e5), d2 = pkfast(e6, e7);      //        8+4lq1+{0..3}
  // send what the partner half needs; receive its counterpart (2 shfl not 4)
  u32 s0v = lq1 ? a : c2;
  u32 s1v = lq1 ? b2 : d2;
  u32 r0 = __shfl_xor(s0v, 32);
  u32 r1 = __shfl_xor(s1v, 32);
  u32x4 fr;
  fr[0] = lq1 ? r0 : a;
  fr[1] = lq1 ? r1 : b2;
  fr[2] = lq1 ? c2 : r0;
  fr[3] = lq1 ? d2 : r1;
  return __builtin_bit_cast(bf16x8, fr);
}

// ---------------------------------------------------------------------------
// W prep: fp32 [d][c] -> bf16 fragment-linear Wf[widx][dt(4)][kc(8)][lane(64)][8]
// ---------------------------------------------------------------------------
__global__ __launch_bounds__(256)
void wprep_kernel(const float* __restrict__ Wq, const float* __restrict__ Wk,
                  const float* __restrict__ Wv, ushort_t* __restrict__ Wf)
{
  const int tid  = blockIdx.x * 256 + threadIdx.x;     // 0..6143
  const int widx = tid >> 11;
  const int r    = tid & 2047;
  const int dt   = r >> 9;
  const int kc   = (r >> 6) & 7;
  const int ln   = r & 63;
  const float* W = (widx == 0) ? Wq : (widx == 1) ? Wk : Wv;
  const float s  = (widx == 0) ? LOG2E : 1.0f;
  const int d    = dt * 32 + (ln & 31);
  const int c0   = kc * 16 + (ln >> 5) * 8;
  const float* p = W + d * C_ + c0;
  f32x4 lo = *(const f32x4*)p, hi = *(const f32x4*)(p + 4);
  float v[8] = { lo.x, lo.y, lo.z, lo.w, hi.x, hi.y, hi.z, hi.w };
  *(bf16x8*)(Wf + (size_t)tid * 8) = pack8(v, s);
}

// ---------------------------------------------------------------------------
// Projection (unchanged — proven correct).
//  Qf/Kf: [b][i32(128)][kc(8)][lane(64)][8]        (lane=i, 8 consecutive d)
//  Vf   : [b][j64(64)][ct(4)][cc(4)][lane(64)][8]  (lane=c, 8 consecutive j)
// ---------------------------------------------------------------------------
__global__ __launch_bounds__(256, 2)
void proj_kernel(const float* __restrict__ x,
                 const float* __restrict__ bq, const float* __restrict__ bk,
                 const float* __restrict__ bv, const ushort_t* __restrict__ Wf,
                 ushort_t* __restrict__ Qf, ushort_t* __restrict__ Kf,
                 ushort_t* __restrict__ Vf)
{
  const int b   = blockIdx.x & 7;
  const int n0  = (blockIdx.x >> 3) << 6;
  const int t   = threadIdx.x;
  const int w   = t >> 6;
  const int lane = t & 63;
  const int l31 = t & 31;
  const int lq1 = (t >> 5) & 1;
  const int pb  = w & 1;

  __shared__ float xs[128 * 65];
  {
    const float* xb = x + (size_t)b * C_ * N_ + n0;
    const int m  = t & 15;
    const int cb = t >> 4;
#pragma unroll
    for (int it = 0; it < 8; ++it) {
      const int c = it * 16 + cb;
      f32x4 v = *(const f32x4*)(xb + (size_t)c * N_ + m * 4);
      *(f32x4*)&xs[c * 65 + m * 4] = v;
    }
  }
  __syncthreads();

  bf16x8 xf[8];
#pragma unroll
  for (int kc = 0; kc < 8; ++kc) {
    float v[8];
#pragma unroll
    for (int e = 0; e < 8; ++e)
      v[e] = xs[(kc * 16 + lq1 * 8 + e) * 65 + pb * 32 + l31];
    xf[kc] = pack8(v, 1.0f);
  }

  const ushort_t* WQf = Wf;
  const ushort_t* WKf = Wf + 16384;
  const ushort_t* WVf = Wf + 32768;
  const f32x16 Z = {0,0,0,0,0,0,0,0,0,0,0,0,0,0,0,0};

  if (w < 2) {
    const int i32 = (n0 >> 5) + pb;
#pragma unroll
    for (int dt = 0; dt < 4; ++dt) {
      f32x16 sq = Z, sk = Z;
#pragma unroll
      for (int kc = 0; kc < 8; ++kc) {
        bf16x8 wq = *(const bf16x8*)(WQf + (size_t)(dt * 8 + kc) * 512 + lane * 8);
        bf16x8 wk = *(const bf16x8*)(WKf + (size_t)(dt * 8 + kc) * 512 + lane * 8);
        sq = MFMA32(wq, xf[kc], sq);     // D[m=d][n=pix]
        sk = MFMA32(wk, xf[kc], sk);
      }
#pragma unroll
      for (int q = 0; q < 4; ++q) {
        const int dbase = dt * 32 + q * 8 + lq1 * 4;
        f32x4 b4q = *(const f32x4*)(bq + dbase);
        f32x4 b4k = *(const f32x4*)(bk + dbase);
        uint2 qs, ks;
        qs.x = pack2bf(sq[4*q+0] + b4q.x * LOG2E, sq[4*q+1] + b4q.y * LOG2E);
        qs.y = pack2bf(sq[4*q+2] + b4q.z * LOG2E, sq[4*q+3] + b4q.w * LOG2E);
        ks.x = pack2bf(sk[4*q+0] + b4k.x, sk[4*q+1] + b4k.y);
        ks.y = pack2bf(sk[4*q+2] + b4k.z, sk[4*q+3] + b4k.w);
        const int kcf = dt * 2 + (q >> 1), h = q & 1;
        const size_t off = ((size_t)((b * 128 + i32) * 8 + kcf) * 64 + h * 32 + l31) * 8 + lq1 * 4;
        *(uint2*)(Qf + off) = qs;
        *(uint2*)(Kf + off) = ks;
      }
    }
  } else {
    // V transposed: D[m=pix][n=d] = x^T * Wv^T
#pragma unroll
    for (int dt = 0; dt < 4; ++dt) {
      f32x16 sv = Z;
#pragma unroll
      for (int kc = 0; kc < 8; ++kc) {
        bf16x8 wv = *(const bf16x8*)(WVf + (size_t)(dt * 8 + kc) * 512 + lane * 8);
        sv = MFMA32(xf[kc], wv, sv);
      }
      const float bvl = bv[dt * 32 + l31];           // lane = d
#pragma unroll
      for (int q = 0; q < 4; ++q) {
        uint2 vs;
        vs.x = pack2bf(sv[4*q+0] + bvl, sv[4*q+1] + bvl);
        vs.y = pack2bf(sv[4*q+2] + bvl, sv[4*q+3] + bvl);
        const int j64 = n0 >> 6;
        const int cc  = pb * 2 + (q >> 1);
        const size_t off = ((size_t)((b * 64 + j64) * 4 + dt) * 4 + cc) * 512 +
                           (size_t)((q & 1) * 32 + l31) * 8 + lq1 * 4;
        *(uint2*)(Vf + off) = vs;
      }
    }
  }
}

// ---------------------------------------------------------------------------
// Flash attention. R7 vs R6 (anti-spill): qf(iblk1) is NOT resident — it is
// re-read from L2 each tile (8 coalesced 1KB loads, issued BEFORE the staging
// DMA so their vmcnt wait does not drain the prefetch; anti-LICM asm keeps
// them in-loop). Peak reg demand ~240 < 256 -> no scratch spill (R6 evidence:
// WRITE_SIZE 117 MB vs 67 nominal = per-tile spill). Also: native exp2,
// 2-shfl P exchange, scalar selects, jblk order staggered by wave parity.
// ---------------------------------------------------------------------------
__global__ __launch_bounds__(256, 2)
void flash_kernel(const ushort_t* __restrict__ Qf, const ushort_t* __restrict__ Kf,
                  const ushort_t* __restrict__ Vf, float* __restrict__ out,
                  float* __restrict__ opart, float* __restrict__ lpart,
                  int js, int tiles_per)
{
  const int b     = blockIdx.x & 7;
  const int itile = (blockIdx.x >> 3) & 15;
  const int jsl   = blockIdx.x >> 7;
  const int t     = threadIdx.x;
  const int wv    = t >> 6;
  const int lane  = t & 63;
  const int l31   = t & 31;
  const int lq1   = (t >> 5) & 1;
  const int i0    = itile * 256 + wv * 64;

  __shared__ __align__(16) short smem[32768];   // 64 KB = 2 x (16K K + 16K V)

  const int jt0 = jsl * tiles_per;
  const ushort_t* Kt0 = Kf + (size_t)b * 524288;
  const ushort_t* Vt0 = Vf + (size_t)b * 524288;

  const int wvh = wv & 1;
  auto stage = [&](int jt, int p) {
    const ushort_t* src = (wv < 2) ? (Kt0 + (size_t)jt * 8192)
                                   : (Vt0 + (size_t)jt * 8192);
    ushort_t* dst = (ushort_t*)smem + p * 16384 + (wv < 2 ? 0 : 8192);
#pragma unroll
    for (int c = 0; c < 8; ++c) {
      const int ch = wvh * 8 + c;
      gload_lds16(src + ch * 512 + lane * 8, dst + ch * 512);
    }
  };

  // Q fragments: iblk0 resident; iblk1 base kept as opaque address (per-tile)
  bf16x8 qf0[8];
  const size_t qb0 = (size_t)((b * 128 + (i0 >> 5)) * 8) * 512;
#pragma unroll
  for (int kc = 0; kc < 8; ++kc)
    qf0[kc] = *(const bf16x8*)(Qf + qb0 + (size_t)kc * 512 + lane * 8);
  const ushort_t* q1base = Qf + (size_t)((b * 128 + (i0 >> 5) + 1) * 8) * 512 +
                           lane * 8;

  const f32x16 Z = {0,0,0,0,0,0,0,0,0,0,0,0,0,0,0,0};
  f32x16 o[2][4] = {{Z,Z,Z,Z},{Z,Z,Z,Z}};
  float ls0 = 0.f, ls1 = 0.f;

  stage(jt0, 0);
  __syncthreads();

  for (int jt = jt0; jt < jt0 + tiles_per; ++jt) {
    const int par = (jt - jt0) & 1;

    // qf1 reload (transient regs): issued FIRST so the compiler's vmcnt wait
    // for them leaves the prefetch DMA (issued next) in flight.
    const ushort_t* q1 = q1base;
    asm volatile("" : "+v"(q1));        // defeat LICM: loads stay in-loop
    bf16x8 qf1[8];
#pragma unroll
    for (int kc = 0; kc < 8; ++kc)
      qf1[kc] = *(const bf16x8*)(q1 + (size_t)kc * 512);

    if (jt + 1 < jt0 + tiles_per) stage(jt + 1, par ^ 1);   // prefetch, no wait

    const short* kbuf = smem + par * 16384;
    const short* vbuf = kbuf + 8192;

#pragma unroll
    for (int jj = 0; jj < 2; ++jj) {
      const int jblk = jj ^ wvh;        // wave-parity stagger breaks convoys
      // ---- S^T = K*Q : D[m=j][n=i] ----
      f32x16 s0 = Z, s1 = Z;
#pragma unroll
      for (int kc = 0; kc < 8; ++kc) {
        bf16x8 kf = *(const bf16x8*)&kbuf[(jblk * 8 + kc) * 512 + lane * 8];
        s0 = MFMA32(kf, qf0[kc], s0);
        s1 = MFMA32(kf, qf1[kc], s1);
      }
      // ---- softmax (no-max, exp2 domain), P packed in regs ----
      bf16x8 pa0[2], pa1[2];
#pragma unroll
      for (int half = 0; half < 2; ++half) pa0[half] = mk_pa(s0, half * 8, ls0, lq1);
#pragma unroll
      for (int half = 0; half < 2; ++half) pa1[half] = mk_pa(s1, half * 8, ls1, lq1);
      // ---- joint PV: V-frag read once, feeds both o[0], o[1] ----
#pragma unroll
      for (int half = 0; half < 2; ++half) {
        const int cc = jblk * 2 + half;
#pragma unroll
        for (int ct = 0; ct < 4; ++ct) {
          bf16x8 vf = *(const bf16x8*)&vbuf[(ct * 4 + cc) * 512 + lane * 8];
          o[0][ct] = MFMA32(vf, pa0[half], o[0][ct]);   // D[m=c][n=i]
          o[1][ct] = MFMA32(vf, pa1[half], o[1][ct]);
        }
      }
    }
    __syncthreads();   // drains prefetch DMA + fences buffer reuse
  }

  ls0 += __shfl_xor(ls0, 32);    // full row sums; lane l31 -> i = i0(+32) + l31
  ls1 += __shfl_xor(ls1, 32);

  // ---- epilogue: coalesced dword stores, per-lane normalization ----
  if (js == 1) {
    const float inv0 = 1.0f / ls0, inv1 = 1.0f / ls1;
#pragma unroll
    for (int iblk = 0; iblk < 2; ++iblk) {
      const float inv = iblk ? inv1 : inv0;
      const int ib = i0 + iblk * 32 + l31;
#pragma unroll
      for (int ct = 0; ct < 4; ++ct)
#pragma unroll
        for (int rg = 0; rg < 16; ++rg) {
          const int c = ct * 32 + (rg >> 2) * 8 + lq1 * 4 + (rg & 3);
          out[(size_t)(b * C_ + c) * N_ + ib] = o[iblk][ct][rg] * inv;
        }
    }
  } else {
    float* op = jsl ? (opart + (size_t)(jsl - 1) * B_ * C_ * N_) : out;
#pragma unroll
    for (int iblk = 0; iblk < 2; ++iblk) {
      const int ib = i0 + iblk * 32 + l31;
#pragma unroll
      for (int ct = 0; ct < 4; ++ct)
#pragma unroll
        for (int rg = 0; rg < 16; ++rg) {
          const int c = ct * 32 + (rg >> 2) * 8 + lq1 * 4 + (rg & 3);
          op[(size_t)(b * C_ + c) * N_ + ib] = o[iblk][ct][rg];
        }
    }
    if (lane < 32) {
      float* lp = lpart + (size_t)jsl * B_ * N_ + (size_t)b * N_;
      lp[i0 + l31]      = ls0;
      lp[i0 + 32 + l31] = ls1;
    }
  }
}

// ---------------------------------------------------------------------------
// Combine: slice 0 lives in `out` (aliased); sums + normalizes in place.
// ---------------------------------------------------------------------------
__global__ __launch_bounds__(256)
void combine_kernel(const float* __restrict__ opart, const float* __restrict__ lpart,
                    float* __restrict__ out, int js)
{
  const int t  = blockIdx.x * 256 + threadIdx.x;
  const int n4 = (t & 1023) * 4;
  const int bc = t >> 10;
  const int b  = bc >> 7;
  const size_t off  = (size_t)bc * N_ + n4;
  const size_t loff = (size_t)b * N_ + n4;
  f32x4 os = *(const f32x4*)(out + off);
  f32x4 ls = *(const f32x4*)(lpart + loff);
  for (int s = 1; s < js; ++s) {
    os += *(const f32x4*)(opart + (size_t)(s - 1) * B_ * C_ * N_ + off);
    ls += *(const f32x4*)(lpart + (size_t)s * B_ * N_ + loff);
  }
  f32x4 r = { os.x / ls.x, os.y / ls.y, os.z / ls.z, os.w / ls.w };
  *(f32x4*)(out + off) = r;
}

// ---------------------------------------------------------------------------
extern "C" void kernel_launch(void* const* d_in, const int* in_sizes, int n_in,
                              void* d_out, int out_size, void* d_ws, size_t ws_size,
                              hipStream_t stream) {
  const float* x  = (const float*)d_in[0];
  const float* Wq = (const float*)d_in[1];
  const float* bq = (const float*)d_in[2];
  const float* Wk = (const float*)d_in[3];
  const float* bk = (const float*)d_in[4];
  const float* Wv = (const float*)d_in[5];
  const float* bv = (const float*)d_in[6];
  float* out = (float*)d_out;

  const size_t nc = (size_t)B_ * N_ * C_;
  ushort_t* qf = (ushort_t*)d_ws;
  ushort_t* kf = qf + nc;
  ushort_t* vf = kf + nc;
  ushort_t* wf = vf + nc;                          // 49152 elems
  const size_t base = (3 * nc + 49152) * sizeof(ushort_t);

  auto need = [&](int jss) {
    return base + (size_t)jss * (size_t)B_ * N_ * 4 +
           (size_t)(jss - 1) * (size_t)B_ * C_ * N_ * 4;   // slice0 = d_out
  };
  const int js = (ws_size >= need(4)) ? 4 : (ws_size >= need(2)) ? 2 : 1;

  float* lpart = (float*)((char*)d_ws + base);
  float* opart = lpart + (size_t)js * B_ * N_;

  hipLaunchKernelGGL(wprep_kernel, dim3(24), dim3(256), 0, stream, Wq, Wk, Wv, wf);
  hipLaunchKernelGGL(proj_kernel, dim3(512), dim3(256), 0, stream,
                     x, bq, bk, bv, wf, qf, kf, vf);
  hipLaunchKernelGGL(flash_kernel, dim3(128 * js), dim3(256), 0, stream,
                     qf, kf, vf, out, opart, lpart, js, 64 / js);
  if (js > 1)
    hipLaunchKernelGGL(combine_kernel, dim3(4096), dim3(256), 0, stream,
                       opart, lpart, out, js);
}

// Round 8
// 171.234 us; speedup vs baseline: 1.4241x; 1.4241x over previous
//
#include <hip/hip_runtime.h>
#include <stdint.h>
#include <math.h>

typedef float  f32x4  __attribute__((ext_vector_type(4)));
typedef float  f32x16 __attribute__((ext_vector_type(16)));
typedef short  bf16x8 __attribute__((ext_vector_type(8)));
typedef unsigned int u32;
typedef unsigned int u32x4 __attribute__((ext_vector_type(4)));
typedef unsigned short ushort_t;

#define MFMA32(a, b, c) __builtin_amdgcn_mfma_f32_32x32x16_bf16((a), (b), (c), 0, 0, 0)

constexpr int B_ = 8, C_ = 128, N_ = 4096;
constexpr float LOG2E = 1.44269504088896340736f;

__device__ __forceinline__ u32 pack2bf(float a, float b) {  // RNE, a->lo16 b->hi16
  u32 ua = __builtin_bit_cast(u32, a);
  u32 ub = __builtin_bit_cast(u32, b);
  ua += 0x7fffu + ((ua >> 16) & 1u);
  ub += 0x7fffu + ((ub >> 16) & 1u);
  return (ua >> 16) | (ub & 0xffff0000u);
}
__device__ __forceinline__ u32 pkfast(float a, float b) {   // round-half-up, 3 ops
  u32 ua = __builtin_bit_cast(u32, a) + 0x8000u;
  u32 ub = __builtin_bit_cast(u32, b) + 0x8000u;
  return __builtin_amdgcn_perm(ub, ua, 0x07060302u);        // [b_hi16 : a_hi16]
}
__device__ __forceinline__ bf16x8 pack8(const float* v, float s) {
  u32x4 d = { pack2bf(v[0]*s, v[1]*s), pack2bf(v[2]*s, v[3]*s),
              pack2bf(v[4]*s, v[5]*s), pack2bf(v[6]*s, v[7]*s) };
  return __builtin_bit_cast(bf16x8, d);
}

// async global -> LDS, 16B per lane; lds dst is wave-uniform base (+lane*16 by HW)
__device__ __forceinline__ void gload_lds16(const ushort_t* g, ushort_t* l) {
  __builtin_amdgcn_global_load_lds(
      (const __attribute__((address_space(1))) void*)g,
      (__attribute__((address_space(3))) void*)l, 16, 0, 0);
}

// exp2 + bf16 pack + cross-half exchange -> one B-operand P fragment (16 j).
// Layout verified through R5-R7 passes.
__device__ __forceinline__ bf16x8 mk_pa(const f32x16& sv, int rb, float& lacc,
                                        int lq1) {
  float e0 = __builtin_amdgcn_exp2f(sv[rb+0]);
  float e1 = __builtin_amdgcn_exp2f(sv[rb+1]);
  float e2 = __builtin_amdgcn_exp2f(sv[rb+2]);
  float e3 = __builtin_amdgcn_exp2f(sv[rb+3]);
  float e4 = __builtin_amdgcn_exp2f(sv[rb+4]);
  float e5 = __builtin_amdgcn_exp2f(sv[rb+5]);
  float e6 = __builtin_amdgcn_exp2f(sv[rb+6]);
  float e7 = __builtin_amdgcn_exp2f(sv[rb+7]);
  lacc += ((e0+e1)+(e2+e3)) + ((e4+e5)+(e6+e7));
  u32 a  = pkfast(e0, e1), b2 = pkfast(e2, e3);
  u32 c2 = pkfast(e4, e5), d2 = pkfast(e6, e7);
  u32 s0v = lq1 ? a : c2;
  u32 s1v = lq1 ? b2 : d2;
  u32 r0 = __shfl_xor(s0v, 32);
  u32 r1 = __shfl_xor(s1v, 32);
  u32x4 fr;
  fr[0] = lq1 ? r0 : a;
  fr[1] = lq1 ? r1 : b2;
  fr[2] = lq1 ? c2 : r0;
  fr[3] = lq1 ? d2 : r1;
  return __builtin_bit_cast(bf16x8, fr);
}

// ---------------------------------------------------------------------------
// W prep: fp32 [d][c] -> bf16 fragment-linear Wf[widx][dt(4)][kc(8)][lane(64)][8]
// ---------------------------------------------------------------------------
__global__ __launch_bounds__(256)
void wprep_kernel(const float* __restrict__ Wq, const float* __restrict__ Wk,
                  const float* __restrict__ Wv, ushort_t* __restrict__ Wf)
{
  const int tid  = blockIdx.x * 256 + threadIdx.x;     // 0..6143
  const int widx = tid >> 11;
  const int r    = tid & 2047;
  const int dt   = r >> 9;
  const int kc   = (r >> 6) & 7;
  const int ln   = r & 63;
  const float* W = (widx == 0) ? Wq : (widx == 1) ? Wk : Wv;
  const float s  = (widx == 0) ? LOG2E : 1.0f;
  const int d    = dt * 32 + (ln & 31);
  const int c0   = kc * 16 + (ln >> 5) * 8;
  const float* p = W + d * C_ + c0;
  f32x4 lo = *(const f32x4*)p, hi = *(const f32x4*)(p + 4);
  float v[8] = { lo.x, lo.y, lo.z, lo.w, hi.x, hi.y, hi.z, hi.w };
  *(bf16x8*)(Wf + (size_t)tid * 8) = pack8(v, s);
}

// ---------------------------------------------------------------------------
// Projection, R8: 32-pixel blocks, grid 1024 (b=blk&7, nt=blk>>3), 256 thr.
// Each wave handles ONE dt-slice (dt = wave id) of Q, K and V, reusing one
// xf fragment set -> 24 MFMA + 24 1KB W-frag loads per wave. 16.9 KB LDS,
// launch_bounds(256,3): 16 waves/CU (was 8).
// Output layouts identical to R5-R7 (proven):
//  Qf/Kf: [b][i32(128)][kc(8)][lane(64)][8]
//  Vf   : [b][j64(64)][ct(4)][cc(4)][lane(64)][8]
// ---------------------------------------------------------------------------
__global__ __launch_bounds__(256, 3)
void proj_kernel(const float* __restrict__ x,
                 const float* __restrict__ bq, const float* __restrict__ bk,
                 const float* __restrict__ bv, const ushort_t* __restrict__ Wf,
                 ushort_t* __restrict__ Qf, ushort_t* __restrict__ Kf,
                 ushort_t* __restrict__ Vf)
{
  const int b   = blockIdx.x & 7;
  const int nt  = blockIdx.x >> 3;        // 32-pixel group, 0..127
  const int n0  = nt << 5;
  const int t   = threadIdx.x;
  const int dt  = t >> 6;                 // wave id = dt slice
  const int lane = t & 63;
  const int l31 = t & 31;
  const int lq1 = (t >> 5) & 1;

  __shared__ float xs[128 * 33];          // 16.9 KB, pad +1
  {
    const float* xb = x + (size_t)b * C_ * N_ + n0;
    const int m  = t & 7;
    const int cb = t >> 3;                // 32 c-rows per pass
#pragma unroll
    for (int it = 0; it < 4; ++it) {
      const int c = it * 32 + cb;
      f32x4 v = *(const f32x4*)(xb + (size_t)c * N_ + m * 4);
      *(f32x4*)&xs[c * 33 + m * 4] = v;
    }
  }
  __syncthreads();

  // x fragment: lane l31 = pixel, lq1 = k-half (A- and B-operand layout)
  bf16x8 xf[8];
#pragma unroll
  for (int kc = 0; kc < 8; ++kc) {
    float v[8];
#pragma unroll
    for (int e = 0; e < 8; ++e)
      v[e] = xs[(kc * 16 + lq1 * 8 + e) * 33 + l31];
    xf[kc] = pack8(v, 1.0f);
  }

  const ushort_t* WQf = Wf;
  const ushort_t* WKf = Wf + 16384;
  const ushort_t* WVf = Wf + 32768;
  const f32x16 Z = {0,0,0,0,0,0,0,0,0,0,0,0,0,0,0,0};

  f32x16 sq = Z, sk = Z, sv = Z;
#pragma unroll
  for (int kc = 0; kc < 8; ++kc) {
    const size_t wo = (size_t)(dt * 8 + kc) * 512 + lane * 8;
    bf16x8 wq = *(const bf16x8*)(WQf + wo);
    bf16x8 wk = *(const bf16x8*)(WKf + wo);
    bf16x8 wvv = *(const bf16x8*)(WVf + wo);
    sq = MFMA32(wq, xf[kc], sq);     // D[m=d][n=pix]
    sk = MFMA32(wk, xf[kc], sk);
    sv = MFMA32(xf[kc], wvv, sv);    // D[m=pix][n=d]
  }

  // ---- Q/K stores (fragment-linear) ----
#pragma unroll
  for (int q = 0; q < 4; ++q) {
    const int dbase = dt * 32 + q * 8 + lq1 * 4;
    f32x4 b4q = *(const f32x4*)(bq + dbase);
    f32x4 b4k = *(const f32x4*)(bk + dbase);
    uint2 qs, ks;
    qs.x = pack2bf(sq[4*q+0] + b4q.x * LOG2E, sq[4*q+1] + b4q.y * LOG2E);
    qs.y = pack2bf(sq[4*q+2] + b4q.z * LOG2E, sq[4*q+3] + b4q.w * LOG2E);
    ks.x = pack2bf(sk[4*q+0] + b4k.x, sk[4*q+1] + b4k.y);
    ks.y = pack2bf(sk[4*q+2] + b4k.z, sk[4*q+3] + b4k.w);
    const int kcf = dt * 2 + (q >> 1), h = q & 1;
    const size_t off = ((size_t)((b * 128 + nt) * 8 + kcf) * 64 + h * 32 + l31) * 8 + lq1 * 4;
    *(uint2*)(Qf + off) = qs;
    *(uint2*)(Kf + off) = ks;
  }

  // ---- V stores ----
  {
    const float bvl = bv[dt * 32 + l31];           // lane = d
    const int j64 = nt >> 1, qp = nt & 1;
#pragma unroll
    for (int q = 0; q < 4; ++q) {
      uint2 vs;
      vs.x = pack2bf(sv[4*q+0] + bvl, sv[4*q+1] + bvl);
      vs.y = pack2bf(sv[4*q+2] + bvl, sv[4*q+3] + bvl);
      const int cc = qp * 2 + (q >> 1);
      const size_t off = ((size_t)((b * 64 + j64) * 4 + dt) * 4 + cc) * 512 +
                         (size_t)((q & 1) * 32 + l31) * 8 + lq1 * 4;
      *(uint2*)(Vf + off) = vs;
    }
  }
}

// ---------------------------------------------------------------------------
// Flash attention, R8: 32 i-rows/wave (o=64 AGPR, qf=32), j-tile 32
// (staging 16 KB, double-buffer 32 KB), launch_bounds(256,3) -> 12 waves/CU
// (3 blocks/CU; R3-R7 all ran 2 waves/SIMD — the latency wall).
// grid = 8b * 32 itiles * js = 256*js blocks; js=3 -> 768 = exactly 3/CU.
// S^T = K*Q (C col=i); P in regs via mk_pa; PV o=MFMA(vf,pa) -> D[m=c][n=i].
// ---------------------------------------------------------------------------
__global__ __launch_bounds__(256, 3)
void flash_kernel(const ushort_t* __restrict__ Qf, const ushort_t* __restrict__ Kf,
                  const ushort_t* __restrict__ Vf, float* __restrict__ out,
                  float* __restrict__ opart, float* __restrict__ lpart, int js)
{
  const int b     = blockIdx.x & 7;
  const int itile = (blockIdx.x >> 3) & 31;
  const int jsl   = blockIdx.x >> 8;
  const int t     = threadIdx.x;
  const int wv    = t >> 6;
  const int lane  = t & 63;
  const int l31   = t & 31;
  const int lq1   = (t >> 5) & 1;
  const int i0    = itile * 128 + wv * 32;

  __shared__ __align__(16) short smem[16384];   // 32 KB = 2 x (8K K + 8K V)

  const int jt0 = (jsl * 128) / js;
  const int jt1 = ((jsl + 1) * 128) / js;
  const ushort_t* Kt0   = Kf + (size_t)b * 524288;
  const ushort_t* Vbase = Vf + (size_t)b * 524288;

  // stage j32-tile jt into buffer p: 16 x 1KB chunks, 4 per wave.
  auto stage = [&](int jt, int p) {
    ushort_t* buf = (ushort_t*)smem + p * 8192;
    if (wv < 2) {                      // K chunks 0..7 (contiguous source)
      const ushort_t* src = Kt0 + (size_t)jt * 4096;
#pragma unroll
      for (int c = 0; c < 4; ++c) {
        const int g = wv * 4 + c;
        gload_lds16(src + g * 512 + lane * 8, buf + g * 512);
      }
    } else {                           // V chunks: (ct, cc = (jt&1)*2 + h)
      const int qp = jt & 1;
      const ushort_t* src = Vbase + (size_t)(jt >> 1) * 8192;
#pragma unroll
      for (int c = 0; c < 4; ++c) {
        const int h2 = (wv - 2) * 4 + c;            // 0..7
        const int ct = h2 >> 1, h = h2 & 1;
        gload_lds16(src + (size_t)(ct * 4 + qp * 2 + h) * 512 + lane * 8,
                    buf + 4096 + h2 * 512);
      }
    }
  };

  // Q fragments (persistent, coalesced): i32-group = itile*4 + wv
  bf16x8 qf[8];
  const size_t qb = (size_t)((b * 128 + itile * 4 + wv) * 8) * 512;
#pragma unroll
  for (int kc = 0; kc < 8; ++kc)
    qf[kc] = *(const bf16x8*)(Qf + qb + (size_t)kc * 512 + lane * 8);

  const f32x16 Z = {0,0,0,0,0,0,0,0,0,0,0,0,0,0,0,0};
  f32x16 o[4] = {Z, Z, Z, Z};
  float lsum = 0.f;

  stage(jt0, 0);
  __syncthreads();

  for (int jt = jt0; jt < jt1; ++jt) {
    const int par = (jt - jt0) & 1;
    if (jt + 1 < jt1) stage(jt + 1, par ^ 1);   // prefetch into other buffer

    const short* kbuf = smem + par * 8192;
    const short* vbuf = kbuf + 4096;

    // ---- S^T = K*Q : D[m=j(32)][n=i(32)] ----
    f32x16 s = Z;
#pragma unroll
    for (int kc = 0; kc < 8; ++kc) {
      bf16x8 kf = *(const bf16x8*)&kbuf[kc * 512 + lane * 8];
      s = MFMA32(kf, qf[kc], s);
    }
    // ---- softmax (no-max, exp2 domain) ----
    bf16x8 pa0 = mk_pa(s, 0, lsum, lq1);
    bf16x8 pa1 = mk_pa(s, 8, lsum, lq1);
    // ---- PV: o[ct] D[m=c][n=i] ----
#pragma unroll
    for (int ct = 0; ct < 4; ++ct) {
      bf16x8 vf0 = *(const bf16x8*)&vbuf[(ct * 2 + 0) * 512 + lane * 8];
      o[ct] = MFMA32(vf0, pa0, o[ct]);
      bf16x8 vf1 = *(const bf16x8*)&vbuf[(ct * 2 + 1) * 512 + lane * 8];
      o[ct] = MFMA32(vf1, pa1, o[ct]);
    }
    __syncthreads();   // drains prefetch DMA + fences buffer reuse
  }

  lsum += __shfl_xor(lsum, 32);   // full row sum; lane l31 -> i = i0 + l31
  const int ib = i0 + l31;

  if (js == 1) {
    const float inv = 1.0f / lsum;
#pragma unroll
    for (int ct = 0; ct < 4; ++ct)
#pragma unroll
      for (int rg = 0; rg < 16; ++rg) {
        const int c = ct * 32 + (rg >> 2) * 8 + lq1 * 4 + (rg & 3);
        out[(size_t)(b * C_ + c) * N_ + ib] = o[ct][rg] * inv;
      }
  } else {
    float* op = jsl ? (opart + (size_t)(jsl - 1) * B_ * C_ * N_) : out;
#pragma unroll
    for (int ct = 0; ct < 4; ++ct)
#pragma unroll
      for (int rg = 0; rg < 16; ++rg) {
        const int c = ct * 32 + (rg >> 2) * 8 + lq1 * 4 + (rg & 3);
        op[(size_t)(b * C_ + c) * N_ + ib] = o[ct][rg];
      }
    if (lane < 32)
      lpart[(size_t)jsl * B_ * N_ + (size_t)b * N_ + ib] = lsum;
  }
}

// ---------------------------------------------------------------------------
// Combine: slice 0 lives in `out` (aliased); sums + normalizes in place.
// ---------------------------------------------------------------------------
__global__ __launch_bounds__(256)
void combine_kernel(const float* __restrict__ opart, const float* __restrict__ lpart,
                    float* __restrict__ out, int js)
{
  const int t  = blockIdx.x * 256 + threadIdx.x;
  const int n4 = (t & 1023) * 4;
  const int bc = t >> 10;
  const int b  = bc >> 7;
  const size_t off  = (size_t)bc * N_ + n4;
  const size_t loff = (size_t)b * N_ + n4;
  f32x4 os = *(const f32x4*)(out + off);
  f32x4 ls = *(const f32x4*)(lpart + loff);
  for (int s = 1; s < js; ++s) {
    os += *(const f32x4*)(opart + (size_t)(s - 1) * B_ * C_ * N_ + off);
    ls += *(const f32x4*)(lpart + (size_t)s * B_ * N_ + loff);
  }
  f32x4 r = { os.x / ls.x, os.y / ls.y, os.z / ls.z, os.w / ls.w };
  *(f32x4*)(out + off) = r;
}

// ---------------------------------------------------------------------------
extern "C" void kernel_launch(void* const* d_in, const int* in_sizes, int n_in,
                              void* d_out, int out_size, void* d_ws, size_t ws_size,
                              hipStream_t stream) {
  const float* x  = (const float*)d_in[0];
  const float* Wq = (const float*)d_in[1];
  const float* bq = (const float*)d_in[2];
  const float* Wk = (const float*)d_in[3];
  const float* bk = (const float*)d_in[4];
  const float* Wv = (const float*)d_in[5];
  const float* bv = (const float*)d_in[6];
  float* out = (float*)d_out;

  const size_t nc = (size_t)B_ * N_ * C_;
  ushort_t* qf = (ushort_t*)d_ws;
  ushort_t* kf = qf + nc;
  ushort_t* vf = kf + nc;
  ushort_t* wf = vf + nc;                          // 49152 elems
  const size_t base = (3 * nc + 49152) * sizeof(ushort_t);

  auto need = [&](int jss) {
    return base + (size_t)jss * (size_t)B_ * N_ * 4 +
           (size_t)(jss - 1) * (size_t)B_ * C_ * N_ * 4;   // slice0 = d_out
  };
  const int js = (ws_size >= need(3)) ? 3 : (ws_size >= need(2)) ? 2 : 1;

  float* lpart = (float*)((char*)d_ws + base);
  float* opart = lpart + (size_t)js * B_ * N_;

  hipLaunchKernelGGL(wprep_kernel, dim3(24), dim3(256), 0, stream, Wq, Wk, Wv, wf);
  hipLaunchKernelGGL(proj_kernel, dim3(1024), dim3(256), 0, stream,
                     x, bq, bk, bv, wf, qf, kf, vf);
  hipLaunchKernelGGL(flash_kernel, dim3(256 * js), dim3(256), 0, stream,
                     qf, kf, vf, out, opart, lpart, js);
  if (js > 1)
    hipLaunchKernelGGL(combine_kernel, dim3(4096), dim3(256), 0, stream,
                       opart, lpart, out, js);
}